// Round 12
// baseline (68.065 us; speedup 1.0000x reference)
//
#include <hip/hip_runtime.h>
#include <hip/hip_bf16.h>
#include <stdint.h>

#define BB 32
#define NN 1024
#define MM 1024
#define DD 256

typedef __attribute__((ext_vector_type(8))) short short8;
typedef __attribute__((ext_vector_type(4))) float floatx4;

__device__ inline unsigned short f2bf(float x) {
    union { __hip_bfloat16 h; unsigned short u; } cv;
    cv.h = __float2bfloat16(x);
    return cv.u;
}
__device__ inline short8 pack8(float4 a, float4 b) {
    short8 o;
    o[0] = f2bf(a.x); o[1] = f2bf(a.y); o[2] = f2bf(a.z); o[3] = f2bf(a.w);
    o[4] = f2bf(b.x); o[5] = f2bf(b.y); o[6] = f2bf(b.z); o[7] = f2bf(b.w);
    return o;
}
// async global->LDS. LDS dest = wave-uniform base; HW adds lane*size.
__device__ inline void async_copy16(void* lds, const void* g) {
    __builtin_amdgcn_global_load_lds(
        (const __attribute__((address_space(1))) unsigned int*)g,
        (__attribute__((address_space(3))) unsigned int*)lds, 16, 0, 0);
}
__device__ inline void async_copy4(void* lds, const void* g) {
    __builtin_amdgcn_global_load_lds(
        (const __attribute__((address_space(1))) unsigned int*)g,
        (__attribute__((address_space(3))) unsigned int*)lds, 4, 0, 0);
}

// ---------------------------------------------------------------------------
// Convert h2 ONLY: fp32 -> bf16 + per-row sum of squares (fp32 exact),
// plus rowmin/colmin init folded in. One wave per TWO rows (32 B/lane).
// ---------------------------------------------------------------------------
__global__ __launch_bounds__(256) void convert_kernel(
        const float* __restrict__ h2, unsigned short* __restrict__ h2b,
        float* __restrict__ sq2, unsigned int* __restrict__ minb) {
    int g = blockIdx.x * 256 + threadIdx.x;
    if (g < 2 * BB * NN) minb[g] = 0x7F800000u;   // +inf

    int wid  = blockIdx.x * 4 + (threadIdx.x >> 6);
    int lane = threadIdx.x & 63;
    int l5   = lane & 31;
    int row  = wid * 2 + (lane >> 5);

    const float4* p = (const float4*)(h2 + (size_t)row * DD) + l5 * 2;
    float4 a = p[0], c = p[1];

    float s = a.x*a.x + a.y*a.y + a.z*a.z + a.w*a.w
            + c.x*c.x + c.y*c.y + c.z*c.z + c.w*c.w;
    #pragma unroll
    for (int off = 16; off; off >>= 1) s += __shfl_xor(s, off, 64);

    *(short8*)((char*)(h2b + (size_t)row * DD) + l5 * 16) = pack8(a, c);
    if (l5 == 0) sq2[row] = s;
}

// ---------------------------------------------------------------------------
// A-resident batched GEMM + fused Hausdorff (r8-proven structure).
// Grid (32 b, 8 n-tiles) = 256 blocks, 1/CU. 512 thr = 8 waves (2n x 4m;
// wave tile 64n x 32m). Prologue: A panel 128x256 staged from h1 fp32 in
// TWO 64 KB halves -> af[4][8] bf16 regs + sq1 by-product (no h1 convert
// pass). LDS A-region reused as B ring bufs 2/3. B (bf16) streamed as
// 16 KB chunks, ring-4, ONE barrier/step, exact counted vmcnt, zero
// non-stage in-loop vmem (colmin via LDS atomics, rowmin in regs,
// sq1/sq2 in LDS).
// ---------------------------------------------------------------------------
__global__ __launch_bounds__(512, 2) void gemm_kernel(
        const float* __restrict__ h1, const unsigned short* __restrict__ h2b,
        const float* __restrict__ sq2,
        unsigned int* __restrict__ rowmin, unsigned int* __restrict__ colmin) {
    __shared__ __align__(16) char pool[98304];
    // [0,64K): A fp32 half-panel (prologue) -> B-bufs 2,3  [64K,96K): B-bufs 0,1
    #define BUF0 (pool + 65536)
    #define BUF1 (pool + 81920)
    #define BUF2 (pool + 0)
    #define BUF3 (pool + 16384)
    __shared__ __align__(16) float  sq1_s[128];
    __shared__ __align__(16) float  sq2_s[1024];
    __shared__ unsigned int cl_s[1024];

    const int b    = blockIdx.x;       // batch; XCD = b%8
    const int tile = blockIdx.y;       // n-tile 0..7
    const int n0   = tile * 128;

    const int tid  = threadIdx.x;
    const int wave = tid >> 6;         // 0..7
    const int lane = tid & 63;
    const int wn   = (wave >> 2) * 64;     // {0,64}
    const int wm   = (wave & 3) * 32;      // {0,32,64,96}

    const char* Ag = (const char*)(h1 + ((size_t)b * NN + n0) * DD);  // 1KB rows
    const char* Bg = (const char*)(h2b + (size_t)b * MM * DD);        // 512B rows

    const int krow = lane >> 4;   // 0..3
    const int rrow = lane & 15;   // 0..15
    const int rx   = rrow & 7;
    const int lrow = krow * 4;
    const int lcol = rrow;

    // colmin LDS init (plain stores; drained before first use)
    cl_s[tid] = 0x7F800000u; cl_s[tid + 512] = 0x7F800000u;

    // ---- prologue: sq2 -> LDS, then A fp32 in two 64 KB halves ----
    #pragma unroll
    for (int t = 0; t < 2; ++t)
        async_copy4((char*)sq2_s + t * 2048 + wave * 256,
                    (const char*)(sq2 + b * MM) + t * 2048 + wave * 256 + lane * 4);

    short8 af[4][8];

    #pragma unroll 1
    for (int half = 0; half < 2; ++half) {
        // stage 64 rows x 1 KB fp32; local slot r holds global row half*64+r,
        // 16B-unit inverse-XOR-swizzled by (r&7)
        #pragma unroll
        for (int t = 0; t < 8; ++t) {
            int r = t * 8 + wave;
            async_copy16(pool + r * 1024,
                         Ag + (size_t)(half * 64 + r) * 1024 + ((lane ^ (r & 7)) << 4));
        }
        asm volatile("s_waitcnt vmcnt(0) lgkmcnt(0)" ::: "memory");
        __builtin_amdgcn_s_barrier();
        __builtin_amdgcn_sched_barrier(0);

        // waves with wn == half*64 extract their af + sq1 by-product
        if ((wave >> 2) == half) {
            float ssum[4] = {0.f, 0.f, 0.f, 0.f};
            #pragma unroll
            for (int i = 0; i < 4; ++i) {
                const char* rp = pool + (size_t)(i * 16 + rrow) * 1024;
                #pragma unroll
                for (int kq = 0; kq < 8; ++kq) {
                    int u0 = kq * 8 + krow * 2;
                    float4 f0 = *(const float4*)(rp + ((u0 ^ rx) << 4));
                    float4 f1 = *(const float4*)(rp + (((u0 + 1) ^ rx) << 4));
                    af[i][kq] = pack8(f0, f1);
                    if ((wave & 3) == 0)
                        ssum[i] += f0.x*f0.x + f0.y*f0.y + f0.z*f0.z + f0.w*f0.w
                                 + f1.x*f1.x + f1.y*f1.y + f1.z*f1.z + f1.w*f1.w;
                }
            }
            if ((wave & 3) == 0) {
                #pragma unroll
                for (int i = 0; i < 4; ++i) {
                    float s = ssum[i];
                    s += __shfl_xor(s, 16, 64);
                    s += __shfl_xor(s, 32, 64);
                    if (lane < 16) sq1_s[wn + i * 16 + rrow] = s;
                }
            }
        }
        asm volatile("s_waitcnt lgkmcnt(0)" ::: "memory");
        __builtin_amdgcn_sched_barrier(0);
        __builtin_amdgcn_s_barrier();
        __builtin_amdgcn_sched_barrier(0);
    }

    // ---- A region dead -> B ring. Stage chunks (16 KB: [128m][64k] bf16,
    //      16 sub-chunks of 1 KB = 8 rows x 128 B; 2 copies/thread) ----
    const int rl  = lane >> 3;            // row within sub-chunk
    const int bcu = (lane & 7) ^ rl;      // inverse-swizzled src 16B unit
    #define STAGE(mt_, ks_, BUFP)                                             \
        {                                                                     \
            _Pragma("unroll")                                                 \
            for (int c = 0; c < 2; ++c) {                                     \
                int ch_ = wave * 2 + c;                                       \
                int r_  = ch_ * 8 + rl;                                       \
                async_copy16((char*)(BUFP) + ch_ * 1024,                      \
                             Bg + (size_t)((mt_) * 128 + r_) * 512            \
                                + (size_t)(ks_) * 128 + (bcu << 4));          \
            }                                                                 \
        }

    STAGE(0, 0, BUF0);
    STAGE(0, 1, BUF1);
    STAGE(0, 2, BUF2);

    float rmin[4][4];
    #pragma unroll
    for (int i = 0; i < 4; ++i)
        #pragma unroll
        for (int r = 0; r < 4; ++r) rmin[i][r] = 3.0e38f;

    // ---- main loop: 8 mt x 4 ks; buffers ring = step % 4 (r8-proven) ----
    #pragma unroll 1
    for (int mt = 0; mt < 8; ++mt) {
        floatx4 acc[4][2] = {};

        #pragma unroll
        for (int ks = 0; ks < 4; ++ks) {
            if (mt == 7 && ks == 2)      { asm volatile("s_waitcnt vmcnt(2)" ::: "memory"); }
            else if (mt == 7 && ks == 3) { asm volatile("s_waitcnt vmcnt(0)" ::: "memory"); }
            else                         { asm volatile("s_waitcnt vmcnt(4)" ::: "memory"); }
            __builtin_amdgcn_s_barrier();
            __builtin_amdgcn_sched_barrier(0);

            // stage step s+3 into ring buffer (s+3)%4
            if (ks == 0)          { STAGE(mt,     3, BUF3); }
            else if (mt < 7) {
                if (ks == 1)      { STAGE(mt + 1, 0, BUF0); }
                else if (ks == 2) { STAGE(mt + 1, 1, BUF1); }
                else              { STAGE(mt + 1, 2, BUF2); }
            }

            // compute step s from ring buffer ks
            const char* Bb = (ks == 0) ? BUF0 : (ks == 1) ? BUF1
                           : (ks == 2) ? BUF2 : BUF3;
            __builtin_amdgcn_s_setprio(1);
            #pragma unroll
            for (int kk = 0; kk < 2; ++kk) {
                const int u = ((kk << 2) | krow) ^ rx;
                short8 bfv[2];
                #pragma unroll
                for (int j = 0; j < 2; ++j)
                    bfv[j] = *(const short8*)(Bb
                             + (size_t)(wm + j * 16 + rrow) * 128 + (u << 4));
                #pragma unroll
                for (int i = 0; i < 4; ++i)
                    #pragma unroll
                    for (int j = 0; j < 2; ++j)
                        acc[i][j] = __builtin_amdgcn_mfma_f32_16x16x32_bf16(
                            af[i][ks * 2 + kk], bfv[j], acc[i][j], 0, 0, 0);
            }
            __builtin_amdgcn_s_setprio(0);
        }

        // ---- per-mt epilogue: regs + LDS only (no vmem!) ----
        float s2v0 = sq2_s[mt * 128 + wm + lcol];
        float s2v1 = sq2_s[mt * 128 + wm + 16 + lcol];

        float cmin0 = 3.0e38f, cmin1 = 3.0e38f;
        #pragma unroll
        for (int i = 0; i < 4; ++i) {
            float4 s1q = *(const float4*)(&sq1_s[wn + i * 16 + lrow]);
            #pragma unroll
            for (int r = 0; r < 4; ++r) {
                float s1x = ((const float*)&s1q)[r];
                float d0 = fmaxf(s1x + s2v0 - 2.0f * acc[i][0][r], 0.0f);
                float d1 = fmaxf(s1x + s2v1 - 2.0f * acc[i][1][r], 0.0f);
                rmin[i][r] = fminf(rmin[i][r], fminf(d0, d1));
                cmin0 = fminf(cmin0, d0);
                cmin1 = fminf(cmin1, d1);
            }
        }
        cmin0 = fminf(cmin0, __shfl_xor(cmin0, 16, 64));
        cmin0 = fminf(cmin0, __shfl_xor(cmin0, 32, 64));
        cmin1 = fminf(cmin1, __shfl_xor(cmin1, 16, 64));
        cmin1 = fminf(cmin1, __shfl_xor(cmin1, 32, 64));
        if (lane < 16) {
            atomicMin(&cl_s[mt * 128 + wm + lcol],      __float_as_uint(cmin0));
            atomicMin(&cl_s[mt * 128 + wm + 16 + lcol], __float_as_uint(cmin1));
        }
    }

    // ---- final rowmin (global atomics, out of loop) ----
    unsigned int* rm = rowmin + b * NN + n0;
    #pragma unroll
    for (int i = 0; i < 4; ++i) {
        #pragma unroll
        for (int r = 0; r < 4; ++r) {
            float v = rmin[i][r];
            #pragma unroll
            for (int off = 1; off < 16; off <<= 1)
                v = fminf(v, __shfl_xor(v, off, 64));
            if (lcol == 0)
                atomicMin(&rm[wn + i * 16 + lrow + r], __float_as_uint(v));
        }
    }

    // ---- colmin flush: LDS -> global (once) ----
    __syncthreads();
    unsigned int* cmg = colmin + b * MM;
    atomicMin(&cmg[tid],       cl_s[tid]);
    atomicMin(&cmg[tid + 512], cl_s[tid + 512]);
    #undef STAGE
    #undef BUF0
    #undef BUF1
    #undef BUF2
    #undef BUF3
}

// ---------------------------------------------------------------------------
__global__ __launch_bounds__(256) void finalize_kernel(
        const unsigned int* __restrict__ rowmin,
        const unsigned int* __restrict__ colmin,
        float* __restrict__ out) {
    int b = blockIdx.x;
    int tid = threadIdx.x;
    float s = 0.0f;
    for (int i = tid; i < NN; i += 256) s += __uint_as_float(rowmin[b * NN + i]);
    for (int i = tid; i < MM; i += 256) s += __uint_as_float(colmin[b * MM + i]);
    #pragma unroll
    for (int off = 32; off; off >>= 1) s += __shfl_xor(s, off, 64);
    __shared__ float wsum[4];
    if ((tid & 63) == 0) wsum[tid >> 6] = s;
    __syncthreads();
    if (tid == 0) out[b] = (wsum[0] + wsum[1] + wsum[2] + wsum[3]) * (1.0f / 1024.0f);
}

// ---------------------------------------------------------------------------
extern "C" void kernel_launch(void* const* d_in, const int* in_sizes, int n_in,
                              void* d_out, int out_size, void* d_ws, size_t ws_size,
                              hipStream_t stream) {
    const float* h1 = (const float*)d_in[0];
    const float* h2 = (const float*)d_in[1];
    float* out = (float*)d_out;

    char* ws = (char*)d_ws;
    unsigned short* h2b = (unsigned short*)ws;                    // 16 MB
    float* sq2          = (float*)(ws + (size_t)BB * MM * DD * 2);
    unsigned int* rowmin = (unsigned int*)(sq2 + BB * MM);        // 128 KB
    unsigned int* colmin = rowmin + BB * NN;                      // 128 KB

    // h2 convert + norms + min-buffer init (rowmin/colmin contiguous)
    hipLaunchKernelGGL(convert_kernel, dim3(4096), dim3(256), 0, stream,
                       h2, h2b, sq2, rowmin);

    hipLaunchKernelGGL(gemm_kernel, dim3(BB, 8), dim3(512), 0, stream,
                       h1, h2b, sq2, rowmin, colmin);

    hipLaunchKernelGGL(finalize_kernel, dim3(BB), dim3(256), 0, stream,
                       rowmin, colmin, out);
}

// Round 13
// 49.128 us; speedup vs baseline: 1.3855x; 1.3855x over previous
//
#include <hip/hip_runtime.h>
#include <hip/hip_bf16.h>
#include <stdint.h>

#define BB 32
#define NN 1024
#define MM 1024
#define DD 256

typedef __attribute__((ext_vector_type(8))) short short8;
typedef __attribute__((ext_vector_type(4))) float floatx4;

__device__ inline unsigned short f2bf(float x) {
    union { __hip_bfloat16 h; unsigned short u; } cv;
    cv.h = __float2bfloat16(x);
    return cv.u;
}
__device__ inline short8 pack8(float4 a, float4 b) {
    short8 o;
    o[0] = f2bf(a.x); o[1] = f2bf(a.y); o[2] = f2bf(a.z); o[3] = f2bf(a.w);
    o[4] = f2bf(b.x); o[5] = f2bf(b.y); o[6] = f2bf(b.z); o[7] = f2bf(b.w);
    return o;
}
// async global->LDS. LDS dest = wave-uniform base; HW adds lane*size.
__device__ inline void async_copy16(void* lds, const void* g) {
    __builtin_amdgcn_global_load_lds(
        (const __attribute__((address_space(1))) unsigned int*)g,
        (__attribute__((address_space(3))) unsigned int*)lds, 16, 0, 0);
}
__device__ inline void async_copy4(void* lds, const void* g) {
    __builtin_amdgcn_global_load_lds(
        (const __attribute__((address_space(1))) unsigned int*)g,
        (__attribute__((address_space(3))) unsigned int*)lds, 4, 0, 0);
}

// ---------------------------------------------------------------------------
// Convert h2 ONLY: fp32 -> bf16 + per-row sum of squares (fp32 exact),
// plus rowmin/colmin init folded in. One wave per TWO rows (32 B/lane).
// ---------------------------------------------------------------------------
__global__ __launch_bounds__(256) void convert_kernel(
        const float* __restrict__ h2, unsigned short* __restrict__ h2b,
        float* __restrict__ sq2, unsigned int* __restrict__ minb) {
    int g = blockIdx.x * 256 + threadIdx.x;
    if (g < 2 * BB * NN) minb[g] = 0x7F800000u;   // +inf

    int wid  = blockIdx.x * 4 + (threadIdx.x >> 6);
    int lane = threadIdx.x & 63;
    int l5   = lane & 31;
    int row  = wid * 2 + (lane >> 5);

    const float4* p = (const float4*)(h2 + (size_t)row * DD) + l5 * 2;
    float4 a = p[0], c = p[1];

    float s = a.x*a.x + a.y*a.y + a.z*a.z + a.w*a.w
            + c.x*c.x + c.y*c.y + c.z*c.z + c.w*c.w;
    #pragma unroll
    for (int off = 16; off; off >>= 1) s += __shfl_xor(s, off, 64);

    *(short8*)((char*)(h2b + (size_t)row * DD) + l5 * 16) = pack8(a, c);
    if (l5 == 0) sq2[row] = s;
}

// ---------------------------------------------------------------------------
// A-resident batched GEMM + fused Hausdorff.
// Grid (32 b, 8 n-tiles) = 256 blocks, 1/CU. 512 thr = 8 waves (2n x 4m;
// wave tile 64n x 32m). Prologue: A 128x256 fp32 staged in FOUR 32 KB
// quarters -> UNIFORM all-thread pack to bf16 LDS panel (+sq1 by-product)
// -> r8-identical unconditional ds_read_b128 af extraction (keeps af
// register-resident; no divergent definition -> no spill).
// Main loop: 16 steps of 32 KB B chunks ([128m][128k] bf16), ring-4,
// ONE barrier/step, counted vmcnt 8/8/4/0, prefetch depth 3,
// zero non-stage in-loop vmem. LDS 136.5 KB.
// ---------------------------------------------------------------------------
__global__ __launch_bounds__(512, 2) void gemm_kernel(
        const float* __restrict__ h1, const unsigned short* __restrict__ h2b,
        const float* __restrict__ sq2,
        unsigned int* __restrict__ rowmin, unsigned int* __restrict__ colmin) {
    __shared__ __align__(16) char pool[131072];
    // [0,32K): A fp32 quarter staging -> later B ring buf0
    // [64K,128K): bf16 A panel (128 x 512 B) -> later B ring bufs 2,3
    // ring: buf k at pool + k*32768
    #define PANEL (pool + 65536)
    __shared__ __align__(16) float  sq1_s[128];
    __shared__ __align__(16) float  sq2_s[1024];
    __shared__ unsigned int cl_s[1024];

    const int b    = blockIdx.x;       // batch; XCD = b%8
    const int tile = blockIdx.y;       // n-tile 0..7
    const int n0   = tile * 128;

    const int tid  = threadIdx.x;
    const int wave = tid >> 6;         // 0..7
    const int lane = tid & 63;
    const int wn   = (wave >> 2) * 64;     // {0,64}
    const int wm   = (wave & 3) * 32;      // {0,32,64,96}

    const char* Ag = (const char*)(h1 + ((size_t)b * NN + n0) * DD);  // 1KB rows
    const char* Bg = (const char*)(h2b + (size_t)b * MM * DD);        // 512B rows

    const int krow = lane >> 4;   // 0..3
    const int rrow = lane & 15;   // 0..15
    const int rx   = rrow & 7;
    const int lrow = krow * 4;
    const int lcol = rrow;

    // colmin LDS init (plain stores; drained by first lgkm wait)
    cl_s[tid] = 0x7F800000u; cl_s[tid + 512] = 0x7F800000u;

    // ---- prologue: sq2 -> LDS ----
    #pragma unroll
    for (int t = 0; t < 2; ++t)
        async_copy4((char*)sq2_s + t * 2048 + wave * 256,
                    (const char*)(sq2 + b * MM) + t * 2048 + wave * 256 + lane * 4);

    // ---- A: 4 quarters of 32 rows x 1 KB fp32 -> pack to bf16 panel ----
    #pragma unroll 1
    for (int q = 0; q < 4; ++q) {
        #pragma unroll
        for (int t = 0; t < 4; ++t) {
            int rl_ = t * 8 + wave;                 // 0..31 (rl_&7 == rg&7)
            async_copy16(pool + rl_ * 1024,
                Ag + (size_t)(q * 32 + rl_) * 1024 + ((lane ^ (rl_ & 7)) << 4));
        }
        asm volatile("s_waitcnt vmcnt(0) lgkmcnt(0)" ::: "memory");
        __builtin_amdgcn_s_barrier();
        __builtin_amdgcn_sched_barrier(0);

        // uniform pack: 16 threads/row, 32 floats each -> 4 bf16 units
        {
            int prow = tid >> 4;                    // 0..31 local row
            int s_   = lane & 15;                   // 16-col-slot
            int rg   = q * 32 + prow;
            const char* rp = pool + prow * 1024;
            float sum = 0.f;
            #pragma unroll
            for (int jj = 0; jj < 2; ++jj) {
                int g0 = s_ * 4 + jj * 2;
                float4 f0 = *(const float4*)(rp + ((g0 ^ (prow & 7)) << 4));
                float4 f1 = *(const float4*)(rp + (((g0 + 1) ^ (prow & 7)) << 4));
                sum += f0.x*f0.x + f0.y*f0.y + f0.z*f0.z + f0.w*f0.w
                     + f1.x*f1.x + f1.y*f1.y + f1.z*f1.z + f1.w*f1.w;
                int ub = s_ * 2 + jj;
                *(short8*)(PANEL + (size_t)rg * 512 + ((ub ^ (prow & 7)) << 4))
                    = pack8(f0, f1);
            }
            sum += __shfl_xor(sum, 1, 64);
            sum += __shfl_xor(sum, 2, 64);
            sum += __shfl_xor(sum, 4, 64);
            sum += __shfl_xor(sum, 8, 64);
            if (s_ == 0) sq1_s[rg] = sum;
        }
        asm volatile("s_waitcnt lgkmcnt(0)" ::: "memory");
        __builtin_amdgcn_sched_barrier(0);
        __builtin_amdgcn_s_barrier();
        __builtin_amdgcn_sched_barrier(0);
    }

    // ---- af extraction: r8-identical, unconditional, all waves ----
    short8 af[4][8];
    #pragma unroll
    for (int i = 0; i < 4; ++i) {
        #pragma unroll
        for (int kq = 0; kq < 8; ++kq) {
            int r = wn + i * 16 + rrow;             // r&7 == rx
            int g = kq * 4 + krow;
            af[i][kq] = *(const short8*)(PANEL + (size_t)r * 512 + ((g ^ rx) << 4));
        }
    }
    asm volatile("s_waitcnt lgkmcnt(0)" ::: "memory");
    __builtin_amdgcn_sched_barrier(0);
    __builtin_amdgcn_s_barrier();
    __builtin_amdgcn_sched_barrier(0);

    // ---- B ring: 32 KB chunk = [128m][128k] bf16; 32 sub-chunks of 1 KB
    //      (4 rows x 256 B); 4 copies/thread per stage ----
    const int br = lane >> 4;            // row within sub-chunk 0..3
    const int bp = lane & 15;            // 16B unit within 256B row
    #define STAGE(s_)                                                         \
        { int mt_ = (s_) >> 1, h_ = (s_) & 1;                                 \
          char* bb_ = pool + ((s_) & 3) * 32768;                              \
          _Pragma("unroll")                                                   \
          for (int c = 0; c < 4; ++c) {                                       \
            int ch_ = wave * 4 + c;                                           \
            int r_  = ch_ * 4 + br;                                           \
            async_copy16(bb_ + ch_ * 1024,                                    \
                Bg + (size_t)(mt_ * 128 + r_) * 512 + h_ * 256                \
                   + ((bp ^ (r_ & 7)) << 4)); } }

    STAGE(0); STAGE(1); STAGE(2);

    float rmin[4][4];
    #pragma unroll
    for (int i = 0; i < 4; ++i)
        #pragma unroll
        for (int r = 0; r < 4; ++r) rmin[i][r] = 3.0e38f;

    // ---- main loop: 16 steps (8 mt x 2 halves); waits 8/8/4/0 ----
    #pragma unroll 1
    for (int mt = 0; mt < 8; ++mt) {
        floatx4 acc[4][2] = {};

        #pragma unroll
        for (int h = 0; h < 2; ++h) {
            const int s = mt * 2 + h;
            if (s < 14)      { asm volatile("s_waitcnt vmcnt(8)" ::: "memory"); }
            else if (s < 15) { asm volatile("s_waitcnt vmcnt(4)" ::: "memory"); }
            else             { asm volatile("s_waitcnt vmcnt(0)" ::: "memory"); }
            __builtin_amdgcn_s_barrier();
            __builtin_amdgcn_sched_barrier(0);

            if (s < 13) STAGE(s + 3);

            const char* Bb = pool + (s & 3) * 32768;
            __builtin_amdgcn_s_setprio(1);
            #pragma unroll
            for (int kk = 0; kk < 4; ++kk) {
                short8 bfv[2];
                #pragma unroll
                for (int j = 0; j < 2; ++j) {
                    int g = kk * 4 + krow;
                    bfv[j] = *(const short8*)(Bb
                             + (size_t)(wm + j * 16 + rrow) * 256 + ((g ^ rx) << 4));
                }
                #pragma unroll
                for (int i = 0; i < 4; ++i)
                    #pragma unroll
                    for (int j = 0; j < 2; ++j)
                        acc[i][j] = __builtin_amdgcn_mfma_f32_16x16x32_bf16(
                            af[i][h * 4 + kk], bfv[j], acc[i][j], 0, 0, 0);
            }
            __builtin_amdgcn_s_setprio(0);
        }

        // ---- per-mt epilogue: regs + LDS only (no vmem!) ----
        float s2v0 = sq2_s[mt * 128 + wm + lcol];
        float s2v1 = sq2_s[mt * 128 + wm + 16 + lcol];

        float cmin0 = 3.0e38f, cmin1 = 3.0e38f;
        #pragma unroll
        for (int i = 0; i < 4; ++i) {
            float4 s1q = *(const float4*)(&sq1_s[wn + i * 16 + lrow]);
            #pragma unroll
            for (int r = 0; r < 4; ++r) {
                float s1x = ((const float*)&s1q)[r];
                float d0 = fmaxf(s1x + s2v0 - 2.0f * acc[i][0][r], 0.0f);
                float d1 = fmaxf(s1x + s2v1 - 2.0f * acc[i][1][r], 0.0f);
                rmin[i][r] = fminf(rmin[i][r], fminf(d0, d1));
                cmin0 = fminf(cmin0, d0);
                cmin1 = fminf(cmin1, d1);
            }
        }
        cmin0 = fminf(cmin0, __shfl_xor(cmin0, 16, 64));
        cmin0 = fminf(cmin0, __shfl_xor(cmin0, 32, 64));
        cmin1 = fminf(cmin1, __shfl_xor(cmin1, 16, 64));
        cmin1 = fminf(cmin1, __shfl_xor(cmin1, 32, 64));
        if (lane < 16) {
            atomicMin(&cl_s[mt * 128 + wm + lcol],      __float_as_uint(cmin0));
            atomicMin(&cl_s[mt * 128 + wm + 16 + lcol], __float_as_uint(cmin1));
        }
    }

    // ---- final rowmin (global atomics, out of loop) ----
    unsigned int* rm = rowmin + b * NN + n0;
    #pragma unroll
    for (int i = 0; i < 4; ++i) {
        #pragma unroll
        for (int r = 0; r < 4; ++r) {
            float v = rmin[i][r];
            #pragma unroll
            for (int off = 1; off < 16; off <<= 1)
                v = fminf(v, __shfl_xor(v, off, 64));
            if (lcol == 0)
                atomicMin(&rm[wn + i * 16 + lrow + r], __float_as_uint(v));
        }
    }

    // ---- colmin flush: LDS -> global (once) ----
    __syncthreads();
    unsigned int* cmg = colmin + b * MM;
    atomicMin(&cmg[tid],       cl_s[tid]);
    atomicMin(&cmg[tid + 512], cl_s[tid + 512]);
    #undef STAGE
    #undef PANEL
}

// ---------------------------------------------------------------------------
__global__ __launch_bounds__(256) void finalize_kernel(
        const unsigned int* __restrict__ rowmin,
        const unsigned int* __restrict__ colmin,
        float* __restrict__ out) {
    int b = blockIdx.x;
    int tid = threadIdx.x;
    float s = 0.0f;
    for (int i = tid; i < NN; i += 256) s += __uint_as_float(rowmin[b * NN + i]);
    for (int i = tid; i < MM; i += 256) s += __uint_as_float(colmin[b * MM + i]);
    #pragma unroll
    for (int off = 32; off; off >>= 1) s += __shfl_xor(s, off, 64);
    __shared__ float wsum[4];
    if ((tid & 63) == 0) wsum[tid >> 6] = s;
    __syncthreads();
    if (tid == 0) out[b] = (wsum[0] + wsum[1] + wsum[2] + wsum[3]) * (1.0f / 1024.0f);
}

// ---------------------------------------------------------------------------
extern "C" void kernel_launch(void* const* d_in, const int* in_sizes, int n_in,
                              void* d_out, int out_size, void* d_ws, size_t ws_size,
                              hipStream_t stream) {
    const float* h1 = (const float*)d_in[0];
    const float* h2 = (const float*)d_in[1];
    float* out = (float*)d_out;

    char* ws = (char*)d_ws;
    unsigned short* h2b = (unsigned short*)ws;                    // 16 MB
    float* sq2          = (float*)(ws + (size_t)BB * MM * DD * 2);
    unsigned int* rowmin = (unsigned int*)(sq2 + BB * MM);        // 128 KB
    unsigned int* colmin = rowmin + BB * NN;                      // 128 KB

    // h2 convert + norms + min-buffer init (rowmin/colmin contiguous)
    hipLaunchKernelGGL(convert_kernel, dim3(4096), dim3(256), 0, stream,
                       h2, h2b, sq2, rowmin);

    hipLaunchKernelGGL(gemm_kernel, dim3(BB, 8), dim3(512), 0, stream,
                       h1, h2b, sq2, rowmin, colmin);

    hipLaunchKernelGGL(finalize_kernel, dim3(BB), dim3(256), 0, stream,
                       rowmin, colmin, out);
}

// Round 14
// 48.955 us; speedup vs baseline: 1.3904x; 1.0035x over previous
//
#include <hip/hip_runtime.h>
#include <hip/hip_bf16.h>
#include <stdint.h>

#define BB 32
#define NN 1024
#define MM 1024
#define DD 256

typedef __attribute__((ext_vector_type(8))) short short8;
typedef __attribute__((ext_vector_type(4))) float floatx4;

__device__ inline unsigned short f2bf(float x) {
    union { __hip_bfloat16 h; unsigned short u; } cv;
    cv.h = __float2bfloat16(x);
    return cv.u;
}
__device__ inline short8 pack8(float4 a, float4 b) {
    short8 o;
    o[0] = f2bf(a.x); o[1] = f2bf(a.y); o[2] = f2bf(a.z); o[3] = f2bf(a.w);
    o[4] = f2bf(b.x); o[5] = f2bf(b.y); o[6] = f2bf(b.z); o[7] = f2bf(b.w);
    return o;
}
// async global->LDS. LDS dest = wave-uniform base; HW adds lane*size.
__device__ inline void async_copy16(void* lds, const void* g) {
    __builtin_amdgcn_global_load_lds(
        (const __attribute__((address_space(1))) unsigned int*)g,
        (__attribute__((address_space(3))) unsigned int*)lds, 16, 0, 0);
}
__device__ inline void async_copy4(void* lds, const void* g) {
    __builtin_amdgcn_global_load_lds(
        (const __attribute__((address_space(1))) unsigned int*)g,
        (__attribute__((address_space(3))) unsigned int*)lds, 4, 0, 0);
}

// ---------------------------------------------------------------------------
// Convert h2 ONLY: fp32 -> bf16 + per-row sum of squares (fp32 exact),
// plus rowmin/colmin init folded in. One wave per TWO rows (32 B/lane).
// ---------------------------------------------------------------------------
__global__ __launch_bounds__(256) void convert_kernel(
        const float* __restrict__ h2, unsigned short* __restrict__ h2b,
        float* __restrict__ sq2, unsigned int* __restrict__ minb) {
    int g = blockIdx.x * 256 + threadIdx.x;
    if (g < 2 * BB * NN) minb[g] = 0x7F800000u;   // +inf

    int wid  = blockIdx.x * 4 + (threadIdx.x >> 6);
    int lane = threadIdx.x & 63;
    int l5   = lane & 31;
    int row  = wid * 2 + (lane >> 5);

    const float4* p = (const float4*)(h2 + (size_t)row * DD) + l5 * 2;
    float4 a = p[0], c = p[1];

    float s = a.x*a.x + a.y*a.y + a.z*a.z + a.w*a.w
            + c.x*c.x + c.y*c.y + c.z*c.z + c.w*c.w;
    #pragma unroll
    for (int off = 16; off; off >>= 1) s += __shfl_xor(s, off, 64);

    *(short8*)((char*)(h2b + (size_t)row * DD) + l5 * 16) = pack8(a, c);
    if (l5 == 0) sq2[row] = s;
}

// ---------------------------------------------------------------------------
// Batched GEMM + fused Hausdorff, LDS-read-ratio optimized.
// Grid (32 b, 8 n-tiles), 512 thr = 8 waves as 2n x 4m; WAVE TILE 64n x 64m
// (acc[4][4]) -> 0.5 ds_read per MFMA (vs 0.75 before). A panel: 128x256
// bf16 in a DEDICATED LDS region (packed once from fp32 quarters, sq1 as
// by-product; never overwritten -> compiler freely remats af, no spill).
// B: 32 KB chunks ([256m][64k] bf16), ring-2, 16 steps total, 2 barriers
// + counted vmcnt(4) per step, stage = only in-loop vmem.
// ---------------------------------------------------------------------------
__global__ __launch_bounds__(512, 2) void gemm_kernel(
        const float* __restrict__ h1, const unsigned short* __restrict__ h2b,
        const float* __restrict__ sq2,
        unsigned int* __restrict__ rowmin, unsigned int* __restrict__ colmin) {
    __shared__ __align__(16) char pool[131072];
    // [0,64K): A bf16 panel (permanent). [64K,128K): staging: fp32 A
    // quarters (32 KB alternating halves), then B ring buf0/buf1.
    #define PANEL (pool)
    #define STG(h_) (pool + 65536 + (h_) * 32768)
    __shared__ __align__(16) float  sq1_s[128];
    __shared__ __align__(16) float  sq2_s[1024];
    __shared__ unsigned int cl_s[1024];
    __shared__ unsigned int rl_s[128];

    const int b    = blockIdx.x;       // batch; all 8 tiles on XCD b%8
    const int tile = blockIdx.y;       // n-tile 0..7
    const int n0   = tile * 128;

    const int tid  = threadIdx.x;
    const int wave = tid >> 6;         // 0..7
    const int lane = tid & 63;
    const int wn   = (wave >> 2) * 64;     // {0,64}
    const int wm   = (wave & 3) * 64;      // {0,64,128,192}

    const char* Ag = (const char*)(h1 + ((size_t)b * NN + n0) * DD);  // 1KB rows
    const char* Bg = (const char*)(h2b + (size_t)b * MM * DD);        // 512B rows

    const int krow = lane >> 4;   // 0..3
    const int rrow = lane & 15;   // 0..15
    const int rx   = rrow & 7;
    const int lrow = krow * 4;
    const int lcol = rrow;

    // LDS min inits (plain stores; drained by prologue lgkm waits)
    cl_s[tid] = 0x7F800000u; cl_s[tid + 512] = 0x7F800000u;
    if (tid < 128) rl_s[tid] = 0x7F800000u;

    // ---- prologue: sq2 -> LDS, pipelined A quarters -> bf16 panel ----
    #pragma unroll
    for (int t = 0; t < 2; ++t)
        async_copy4((char*)sq2_s + t * 2048 + wave * 256,
                    (const char*)(sq2 + b * MM) + t * 2048 + wave * 256 + lane * 4);

    // stage quarter q (32 rows x 1 KB fp32) into STG(q&1); 4 copies/thread
    #define STAGE_A(q_)                                                       \
        { _Pragma("unroll")                                                   \
          for (int t = 0; t < 4; ++t) {                                       \
            int rl_ = t * 8 + wave;                                           \
            async_copy16(STG((q_) & 1) + rl_ * 1024,                          \
                Ag + (size_t)((q_) * 32 + rl_) * 1024                         \
                   + ((lane ^ (rl_ & 7)) << 4)); } }

    STAGE_A(0);
    #pragma unroll 1
    for (int q = 0; q < 4; ++q) {
        if (q < 3) STAGE_A(q + 1);
        if (q < 3) { asm volatile("s_waitcnt vmcnt(4)" ::: "memory"); }
        else       { asm volatile("s_waitcnt vmcnt(0)" ::: "memory"); }
        __builtin_amdgcn_s_barrier();
        __builtin_amdgcn_sched_barrier(0);

        // uniform pack: 16 threads/row, 32 floats each -> bf16 panel + sq1
        {
            int prow = tid >> 4;                    // 0..31 local row
            int s_   = lane & 15;
            int rg   = q * 32 + prow;
            const char* rp = STG(q & 1) + prow * 1024;
            float sum = 0.f;
            #pragma unroll
            for (int jj = 0; jj < 2; ++jj) {
                int g0 = s_ * 4 + jj * 2;
                float4 f0 = *(const float4*)(rp + ((g0 ^ (prow & 7)) << 4));
                float4 f1 = *(const float4*)(rp + (((g0 + 1) ^ (prow & 7)) << 4));
                sum += f0.x*f0.x + f0.y*f0.y + f0.z*f0.z + f0.w*f0.w
                     + f1.x*f1.x + f1.y*f1.y + f1.z*f1.z + f1.w*f1.w;
                int ub = s_ * 2 + jj;
                *(short8*)(PANEL + (size_t)rg * 512 + ((ub ^ (prow & 7)) << 4))
                    = pack8(f0, f1);
            }
            sum += __shfl_xor(sum, 1, 64);
            sum += __shfl_xor(sum, 2, 64);
            sum += __shfl_xor(sum, 4, 64);
            sum += __shfl_xor(sum, 8, 64);
            if (s_ == 0) sq1_s[rg] = sum;
        }
        asm volatile("s_waitcnt lgkmcnt(0)" ::: "memory");
        __builtin_amdgcn_sched_barrier(0);
        __builtin_amdgcn_s_barrier();
        __builtin_amdgcn_sched_barrier(0);
    }

    // ---- B ring: chunk = [256m][64k] bf16 = 32 KB; 32 sub-chunks of
    //      1 KB (8 rows x 128 B); 4 copies/thread per stage ----
    const int rl  = lane >> 3;            // row within sub-chunk 0..7
    const int bcu = (lane & 7) ^ rl;      // inverse-swizzled src 16B unit
    #define STAGE_B(s_)                                                       \
        { int mt_ = (s_) >> 2, ks_ = (s_) & 3;                                \
          char* bb_ = STG((s_) & 1);                                          \
          _Pragma("unroll")                                                   \
          for (int c = 0; c < 4; ++c) {                                       \
            int ch_ = wave * 4 + c;                                           \
            int r_  = ch_ * 8 + rl;                                           \
            async_copy16(bb_ + ch_ * 1024,                                    \
                Bg + (size_t)(mt_ * 256 + r_) * 512 + ks_ * 128               \
                   + (bcu << 4)); } }

    STAGE_B(0); STAGE_B(1);

    float rmin[4][4];
    #pragma unroll
    for (int i = 0; i < 4; ++i)
        #pragma unroll
        for (int r = 0; r < 4; ++r) rmin[i][r] = 3.0e38f;

    // ---- main loop: 4 m-chunks x 4 k-steps = 16 steps; ring-2 ----
    #pragma unroll 1
    for (int mt = 0; mt < 4; ++mt) {
        floatx4 acc[4][4] = {};

        #pragma unroll
        for (int ks = 0; ks < 4; ++ks) {
            const int s = mt * 4 + ks;
            if (s < 15) { asm volatile("s_waitcnt vmcnt(4)" ::: "memory"); }
            else        { asm volatile("s_waitcnt vmcnt(0)" ::: "memory"); }
            __builtin_amdgcn_s_barrier();
            __builtin_amdgcn_sched_barrier(0);

            const char* Bb = STG(s & 1);
            __builtin_amdgcn_s_setprio(1);
            #pragma unroll
            for (int kk = 0; kk < 2; ++kk) {
                short8 af_t[4], bfv[4];
                #pragma unroll
                for (int i = 0; i < 4; ++i) {
                    int g = (ks * 2 + kk) * 4 + krow;        // 16B unit 0..31
                    af_t[i] = *(const short8*)(PANEL
                        + (size_t)(wn + i * 16 + rrow) * 512 + ((g ^ rx) << 4));
                }
                #pragma unroll
                for (int j = 0; j < 4; ++j) {
                    int g = kk * 4 + krow;                   // 16B unit 0..7
                    bfv[j] = *(const short8*)(Bb
                        + (size_t)(wm + j * 16 + rrow) * 128 + ((g ^ rx) << 4));
                }
                #pragma unroll
                for (int i = 0; i < 4; ++i)
                    #pragma unroll
                    for (int j = 0; j < 4; ++j)
                        acc[i][j] = __builtin_amdgcn_mfma_f32_16x16x32_bf16(
                            af_t[i], bfv[j], acc[i][j], 0, 0, 0);
            }
            __builtin_amdgcn_s_setprio(0);

            asm volatile("s_waitcnt lgkmcnt(0)" ::: "memory");
            __builtin_amdgcn_sched_barrier(0);
            __builtin_amdgcn_s_barrier();
            if (s < 14) STAGE_B(s + 2);
        }

        // ---- per-mt epilogue: regs + LDS only (no vmem!) ----
        float s2v[4];
        #pragma unroll
        for (int j = 0; j < 4; ++j)
            s2v[j] = sq2_s[mt * 256 + wm + j * 16 + lcol];

        float cmin[4] = {3.0e38f, 3.0e38f, 3.0e38f, 3.0e38f};
        #pragma unroll
        for (int i = 0; i < 4; ++i) {
            float4 s1q = *(const float4*)(&sq1_s[wn + i * 16 + lrow]);
            #pragma unroll
            for (int r = 0; r < 4; ++r) {
                float s1x = ((const float*)&s1q)[r];
                float pm = 3.0e38f;
                #pragma unroll
                for (int j = 0; j < 4; ++j) {
                    float d = fmaxf(s1x + s2v[j] - 2.0f * acc[i][j][r], 0.0f);
                    pm = fminf(pm, d);
                    cmin[j] = fminf(cmin[j], d);
                }
                rmin[i][r] = fminf(rmin[i][r], pm);
            }
        }
        #pragma unroll
        for (int j = 0; j < 4; ++j) {
            float c = cmin[j];
            c = fminf(c, __shfl_xor(c, 16, 64));
            c = fminf(c, __shfl_xor(c, 32, 64));
            if (lane < 16)
                atomicMin(&cl_s[mt * 256 + wm + j * 16 + lcol],
                          __float_as_uint(c));
        }
    }

    // ---- rowmin combine (LDS) + plain/global stores ----
    #pragma unroll
    for (int i = 0; i < 4; ++i) {
        #pragma unroll
        for (int r = 0; r < 4; ++r) {
            float v = rmin[i][r];
            #pragma unroll
            for (int off = 1; off < 16; off <<= 1)
                v = fminf(v, __shfl_xor(v, off, 64));
            if (lcol == 0)
                atomicMin(&rl_s[wn + i * 16 + lrow + r], __float_as_uint(v));
        }
    }
    __syncthreads();

    unsigned int* cmg = colmin + b * MM;
    atomicMin(&cmg[tid],       cl_s[tid]);
    atomicMin(&cmg[tid + 512], cl_s[tid + 512]);
    if (tid < 128) rowmin[b * NN + n0 + tid] = rl_s[tid];
    #undef STAGE_A
    #undef STAGE_B
    #undef PANEL
    #undef STG
}

// ---------------------------------------------------------------------------
__global__ __launch_bounds__(256) void finalize_kernel(
        const unsigned int* __restrict__ rowmin,
        const unsigned int* __restrict__ colmin,
        float* __restrict__ out) {
    int b = blockIdx.x;
    int tid = threadIdx.x;
    float s = 0.0f;
    for (int i = tid; i < NN; i += 256) s += __uint_as_float(rowmin[b * NN + i]);
    for (int i = tid; i < MM; i += 256) s += __uint_as_float(colmin[b * MM + i]);
    #pragma unroll
    for (int off = 32; off; off >>= 1) s += __shfl_xor(s, off, 64);
    __shared__ float wsum[4];
    if ((tid & 63) == 0) wsum[tid >> 6] = s;
    __syncthreads();
    if (tid == 0) out[b] = (wsum[0] + wsum[1] + wsum[2] + wsum[3]) * (1.0f / 1024.0f);
}

// ---------------------------------------------------------------------------
extern "C" void kernel_launch(void* const* d_in, const int* in_sizes, int n_in,
                              void* d_out, int out_size, void* d_ws, size_t ws_size,
                              hipStream_t stream) {
    const float* h1 = (const float*)d_in[0];
    const float* h2 = (const float*)d_in[1];
    float* out = (float*)d_out;

    char* ws = (char*)d_ws;
    unsigned short* h2b = (unsigned short*)ws;                    // 16 MB
    float* sq2          = (float*)(ws + (size_t)BB * MM * DD * 2);
    unsigned int* rowmin = (unsigned int*)(sq2 + BB * MM);        // 128 KB
    unsigned int* colmin = rowmin + BB * NN;                      // 128 KB

    // h2 convert + norms + min-buffer init (rowmin/colmin contiguous)
    hipLaunchKernelGGL(convert_kernel, dim3(4096), dim3(256), 0, stream,
                       h2, h2b, sq2, rowmin);

    hipLaunchKernelGGL(gemm_kernel, dim3(BB, 8), dim3(512), 0, stream,
                       h1, h2b, sq2, rowmin, colmin);

    hipLaunchKernelGGL(finalize_kernel, dim3(BB), dim3(256), 0, stream,
                       rowmin, colmin, out);
}